// Round 7
// baseline (386.684 us; speedup 1.0000x reference)
//
#include <hip/hip_runtime.h>
#include <stdint.h>

#define DIM 64
#define KC 1024
#define ROWS_PER_BLOCK 512
#define TAU 8.0e-3f        // flag row if score margin < TAU (c_lo dropped => err std ~7e-4)
#define FLAG_CAP 65536

typedef float f32x4 __attribute__((ext_vector_type(4)));
typedef short short8 __attribute__((ext_vector_type(8)));

__device__ __forceinline__ unsigned short bf16_rn(float f) {
  union { float f; uint32_t u; } v; v.f = f;
  uint32_t u = v.u;
  uint32_t r = u + 0x7fffu + ((u >> 16) & 1u);
  return (unsigned short)(r >> 16);
}
__device__ __forceinline__ void gll16(const void* g, void* l) {
  __builtin_amdgcn_global_load_lds(
      (const __attribute__((address_space(1))) void*)g,
      (__attribute__((address_space(3))) void*)l, 16, 0, 0);
}

// K1: codebook -> bf16 (RN), csqh = -0.5*sum(c^2) exact f32, zero counter.
__global__ void k1_prep(const float* __restrict__ cb,
                        unsigned short* __restrict__ cb_hi,
                        float* __restrict__ csqh,
                        int* __restrict__ cnt) {
  const int k = blockIdx.x, j = threadIdx.x;
  const float c = cb[k * DIM + j];
  cb_hi[k * DIM + j] = bf16_rn(c);
  float s = c * c;
  #pragma unroll
  for (int off = 32; off >= 1; off >>= 1) s += __shfl_xor(s, off);
  if (j == 0) csqh[k] = -0.5f * s;
  if (k == 0 && j == 0) *cnt = 0;
}

// K2: LDS-resident codebook (128KB, XOR-swizzled), barrier-free code loop.
// 1024 threads = 16 waves; each wave owns 32 rows; all waves scan all 1024 codes.
// acc = (zhi+zlo)*c_hi - 0.5*c^2; argmin dist == argmax acc. Fused: loss partial
// (||z-e||^2 = ||z||^2 - 2*m1) and z_q gather/write.
__launch_bounds__(1024, 4)
__global__ void k2_argmin(const float* __restrict__ z,
                          const unsigned short* __restrict__ cb_hi,
                          const float* __restrict__ csqh,
                          const float* __restrict__ cb,
                          float* __restrict__ out_idx,
                          float* __restrict__ zq,
                          int* __restrict__ cnt,
                          int* __restrict__ flags,
                          float* __restrict__ partials) {
  __shared__ unsigned short lds_cb[KC * DIM];   // 128 KB, [code][chunk slot] swizzled
  __shared__ float lds_csq[KC];                 // 4 KB; reused as idxL after main loop
  __shared__ float wpart[16];

  const int tid  = threadIdx.x;
  const int lane = tid & 63;
  const int wv   = tid >> 6;    // 0..15
  const int lg   = lane >> 4;   // k-chunk group
  const int lr   = lane & 15;
  const int row0 = blockIdx.x * ROWS_PER_BLOCK;

  // Stage codebook: slot (cl, ch) holds global chunk ch^(cl&7)  (XOR involution,
  // pre-swizzled global source, linear LDS dest per gll16 rule).
  #pragma unroll
  for (int p = 0; p < 8; ++p) {
    const int linear = p * 1024 + tid;
    const int ch = linear & 7;
    const int cl = linear >> 3;
    gll16(cb_hi + cl * DIM + ((ch ^ (cl & 7)) * 8), (char*)lds_cb + linear * 16);
  }
  if (tid < KC / 4) ((f32x4*)lds_csq)[tid] = ((const f32x4*)csqh)[tid];

  // Z fragments: hi = trunc, lo = RN(resid) via v_cvt_pk_bf16_f32; also ||z||^2.
  short8 zhi[2][2], zlo[2][2];
  float zsq[2];
  #pragma unroll
  for (int rt = 0; rt < 2; ++rt) {
    const int row = row0 + wv * 32 + rt * 16 + lr;
    float sq = 0.0f;
    #pragma unroll
    for (int ks = 0; ks < 2; ++ks) {
      const float* p = z + (size_t)row * DIM + ks * 32 + lg * 8;
      const f32x4 va = *(const f32x4*)p;
      const f32x4 vb = *(const f32x4*)(p + 4);
      sq = fmaf(va[0], va[0], sq); sq = fmaf(va[1], va[1], sq);
      sq = fmaf(va[2], va[2], sq); sq = fmaf(va[3], va[3], sq);
      sq = fmaf(vb[0], vb[0], sq); sq = fmaf(vb[1], vb[1], sq);
      sq = fmaf(vb[2], vb[2], sq); sq = fmaf(vb[3], vb[3], sq);
      union { uint32_t w[4]; short8 s8; } H, L;
      #pragma unroll
      for (int pr = 0; pr < 4; ++pr) {
        const float f0 = (pr < 2) ? va[2 * pr]     : vb[2 * pr - 4];
        const float f1 = (pr < 2) ? va[2 * pr + 1] : vb[2 * pr - 3];
        const uint32_t u0 = __float_as_uint(f0);
        const uint32_t u1 = __float_as_uint(f1);
        H.w[pr] = __builtin_amdgcn_perm(u1, u0, 0x07060302u);  // {u1.hi16, u0.hi16}
        const float l0 = f0 - __uint_as_float(u0 & 0xffff0000u);
        const float l1 = f1 - __uint_as_float(u1 & 0xffff0000u);
        uint32_t lw;
        asm("v_cvt_pk_bf16_f32 %0, %1, %2" : "=v"(lw) : "v"(l0), "v"(l1));
        L.w[pr] = lw;
      }
      zhi[rt][ks] = H.s8;
      zlo[rt][ks] = L.s8;
    }
    zsq[rt] = sq;
  }

  float M1[2] = {-3.0e38f, -3.0e38f}, M2[2] = {-3.0e38f, -3.0e38f};
  int I1[2] = {0, 0};

  __syncthreads();   // codebook + csq resident; ONLY barrier before epilogue

  // swizzle XOR is loop-invariant: (ct*16+lr)&7 == lr&7
  const int off0 = lr * 128 + ((lg)     ^ (lr & 7)) * 16;
  const int off1 = lr * 128 + ((4 + lg) ^ (lr & 7)) * 16;

  #pragma unroll 2
  for (int ct = 0; ct < KC / 16; ++ct) {
    const int cbase = ct * 16 + lg * 4;
    const f32x4 init = *(const f32x4*)&lds_csq[cbase];   // -0.5*c^2 per acc reg
    const char* base = (const char*)lds_cb + ct * 2048;
    const short8 cf0 = *(const short8*)(base + off0);    // K chunk 0..31
    const short8 cf1 = *(const short8*)(base + off1);    // K chunk 32..63
    #pragma unroll
    for (int rt = 0; rt < 2; ++rt) {
      f32x4 acc = init;
      acc = __builtin_amdgcn_mfma_f32_16x16x32_bf16(cf0, zhi[rt][0], acc, 0, 0, 0);
      acc = __builtin_amdgcn_mfma_f32_16x16x32_bf16(cf1, zhi[rt][1], acc, 0, 0, 0);
      acc = __builtin_amdgcn_mfma_f32_16x16x32_bf16(cf0, zlo[rt][0], acc, 0, 0, 0);
      acc = __builtin_amdgcn_mfma_f32_16x16x32_bf16(cf1, zlo[rt][1], acc, 0, 0, 0);
      #pragma unroll
      for (int j = 0; j < 4; ++j) {
        const float s = acc[j];
        M2[rt] = __builtin_amdgcn_fmed3f(s, M1[rt], M2[rt]);  // invariant M1>=M2
        const bool take = s > M1[rt];
        M1[rt] = fmaxf(s, M1[rt]);
        I1[rt] = take ? (cbase + j) : I1[rt];
      }
    }
  }

  // Cross-lane combine over lg groups (^16, ^32); butterfly => all lanes hold result.
  float M1b[2], M2b[2], loss01 = 0.0f;
  int idxr[2];
  #pragma unroll
  for (int rt = 0; rt < 2; ++rt) {
    float m1 = M1[rt], m2 = M2[rt];
    int i1 = I1[rt];
    #pragma unroll
    for (int off = 16; off <= 32; off <<= 1) {
      const float o1 = __shfl_xor(m1, off);
      const float o2 = __shfl_xor(m2, off);
      const int   oi = __shfl_xor(i1, off);
      m2 = fmaxf(fmaxf(m2, o2), fminf(m1, o1));
      const bool take = (o1 > m1) || (o1 == m1 && oi < i1);
      if (take) { m1 = o1; i1 = oi; }
    }
    float zs = zsq[rt];
    zs += __shfl_xor(zs, 16);
    zs += __shfl_xor(zs, 32);
    M1b[rt] = m1; M2b[rt] = m2; idxr[rt] = i1;
    loss01 += zs - 2.0f * m1;           // ||z-e||^2 (x4 duplicated across lg groups)
  }

  __syncthreads();   // all waves past csq reads -> safe to overlay idxL
  int* idxL = (int*)lds_csq;
  if (lane < 16) {
    #pragma unroll
    for (int rt = 0; rt < 2; ++rt) {
      const int r = wv * 32 + rt * 16 + lr;
      out_idx[row0 + r] = (float)idxr[rt];
      idxL[r] = idxr[rt];
      if (M1b[rt] - M2b[rt] < TAU) {    // ambiguous vs dropped-c_lo error -> rescue
        const int p = atomicAdd(cnt, 1);
        if (p < FLAG_CAP) flags[p] = row0 + r;
      }
    }
  }
  float lsum = loss01;
  #pragma unroll
  for (int off = 1; off <= 32; off <<= 1) lsum += __shfl_xor(lsum, off);
  if (lane == 0) wpart[wv] = lsum * 0.25f;   // /4: lg-group duplication
  __syncthreads();
  if (tid == 0) {
    float s = 0.0f;
    #pragma unroll
    for (int i = 0; i < 16; ++i) s += wpart[i];
    partials[blockIdx.x] = s;
  }
  // z_q gather + write (2 threads per row, exact f32 codebook rows)
  {
    const int r2 = tid >> 1, half = tid & 1;
    const int idx = idxL[r2];
    const f32x4* src = (const f32x4*)(cb + (size_t)idx * DIM + half * 32);
    f32x4* dst = (f32x4*)(zq + (size_t)(row0 + r2) * DIM + half * 32);
    dst[0] = src[0];
    dst[1] = src[1];
  }
}

// K3: exact f32 re-argmin for flagged rows, one wave per row; fixes out_idx AND z_q.
__global__ void k3_rescue(const float* __restrict__ z,
                          const float* __restrict__ cb,
                          const float* __restrict__ csqh,
                          float* __restrict__ out_idx,
                          float* __restrict__ zq,
                          const int* __restrict__ cnt,
                          const int* __restrict__ flags) {
  int n = *cnt;
  if (n > FLAG_CAP) n = FLAG_CAP;
  const int lane = threadIdx.x & 63;
  const int w = blockIdx.x * 4 + (threadIdx.x >> 6);
  for (int i = w; i < n; i += gridDim.x * 4) {
    const int row = flags[i];
    const f32x4* zr4 = (const f32x4*)(z + (size_t)row * DIM);
    float m1 = -3.0e38f;
    int i1 = 0;
    for (int kk = 0; kk < 16; ++kk) {
      const int k = lane * 16 + kk;
      const f32x4* cp = (const f32x4*)(cb + (size_t)k * DIM);
      float acc = csqh[k];
      #pragma unroll
      for (int j4 = 0; j4 < DIM / 4; ++j4) {
        const f32x4 c4 = cp[j4];
        const f32x4 z4 = zr4[j4];
        acc = fmaf(z4[0], c4[0], acc);
        acc = fmaf(z4[1], c4[1], acc);
        acc = fmaf(z4[2], c4[2], acc);
        acc = fmaf(z4[3], c4[3], acc);
      }
      if (acc > m1) { m1 = acc; i1 = k; }
    }
    #pragma unroll
    for (int off = 32; off >= 1; off >>= 1) {      // butterfly: all lanes get winner
      const float o1 = __shfl_xor(m1, off);
      const int   oi = __shfl_xor(i1, off);
      if (o1 > m1 || (o1 == m1 && oi < i1)) { m1 = o1; i1 = oi; }
    }
    if (lane == 0) out_idx[row] = (float)i1;
    if (lane < 16)
      ((f32x4*)(zq + (size_t)row * DIM))[lane] =
          ((const f32x4*)(cb + (size_t)i1 * DIM))[lane];
  }
}

// K5: reduce 256 block partials -> loss (single block, deterministic tree)
__global__ void k5_reduce(const float* __restrict__ partials,
                          float* __restrict__ loss_slot,
                          float scale, int nb) {
  __shared__ float wsum[4];
  const int tid = threadIdx.x;
  float s = 0.0f;
  for (int i = tid; i < nb / 4; i += 256) {
    const f32x4 v = ((const f32x4*)partials)[i];
    s += (v[0] + v[1]) + (v[2] + v[3]);
  }
  #pragma unroll
  for (int off = 32; off >= 1; off >>= 1) s += __shfl_xor(s, off);
  if ((tid & 63) == 0) wsum[tid >> 6] = s;
  __syncthreads();
  if (tid == 0) *loss_slot = (wsum[0] + wsum[1] + wsum[2] + wsum[3]) * scale;
}

extern "C" void kernel_launch(void* const* d_in, const int* in_sizes, int n_in,
                              void* d_out, int out_size, void* d_ws, size_t ws_size,
                              hipStream_t stream) {
  const float* z  = (const float*)d_in[0];
  const float* cb = (const float*)d_in[1];
  const int N = in_sizes[0] / DIM;  // 131072

  float* out       = (float*)d_out;
  float* out_idx   = out;                          // [0, N): indices as float
  float* zq        = out + N;                      // [N, N + N*64): z_q
  float* loss_slot = out + N + (size_t)N * DIM;    // last element: vq_loss

  unsigned short* cb_hi = (unsigned short*)d_ws;   // 128 KB
  float* csqh = (float*)(cb_hi + KC * DIM);        // 4 KB
  int* cnt    = (int*)(csqh + KC);                 // 256 B slot
  float* partials = (float*)(cnt + 64);            // 1 KB (256 blocks)
  int* flags  = (int*)(partials + 256);            // 256 KB

  const int nb2 = N / ROWS_PER_BLOCK;              // 256 blocks
  const float scale = 1.25f / ((float)N * (float)DIM);  // (1+BETA)/(N*d)

  k1_prep<<<KC, DIM, 0, stream>>>(cb, cb_hi, csqh, cnt);
  k2_argmin<<<nb2, 1024, 0, stream>>>(z, cb_hi, csqh, cb, out_idx, zq, cnt, flags, partials);
  k3_rescue<<<256, 256, 0, stream>>>(z, cb, csqh, out_idx, zq, cnt, flags);
  k5_reduce<<<1, 256, 0, stream>>>(partials, loss_slot, scale, nb2);
}

// Round 8
// 201.857 us; speedup vs baseline: 1.9156x; 1.9156x over previous
//
#include <hip/hip_runtime.h>
#include <stdint.h>

#define DIM 64
#define KC 1024
#define HALF 512
#define ROWS_PER_BLOCK 512
#define TAU 5.0e-4f        // margin on acc scale (=dist/2); k2 err std ~6e-7 after 3-split
typedef float f32x4 __attribute__((ext_vector_type(4)));
typedef short short8 __attribute__((ext_vector_type(8)));

__device__ __forceinline__ unsigned short bf16_rn(float f) {
  union { float f; uint32_t u; } v; v.f = f;
  uint32_t u = v.u;
  uint32_t r = u + 0x7fffu + ((u >> 16) & 1u);
  return (unsigned short)(r >> 16);
}
__device__ __forceinline__ float bf16_f32(unsigned short h) {
  union { uint32_t u; float f; } v; v.u = ((uint32_t)h) << 16;
  return v.f;
}
__device__ __forceinline__ void gll16(const void* g, void* l) {
  __builtin_amdgcn_global_load_lds(
      (const __attribute__((address_space(1))) void*)g,
      (__attribute__((address_space(3))) void*)l, 16, 0, 0);
}

// K1: codebook -> bf16 hi/lo split, csqh = -0.5*sum(c^2) exact f32.
__global__ void k1_prep(const float* __restrict__ cb,
                        unsigned short* __restrict__ cb_hi,
                        unsigned short* __restrict__ cb_lo,
                        float* __restrict__ csqh) {
  const int k = blockIdx.x, j = threadIdx.x;
  const float c = cb[k * DIM + j];
  const unsigned short hi = bf16_rn(c);
  const float hif = bf16_f32(hi);
  cb_hi[k * DIM + j] = hi;
  cb_lo[k * DIM + j] = bf16_rn(c - hif);
  float s = c * c;
  #pragma unroll
  for (int off = 32; off >= 1; off >>= 1) s += __shfl_xor(s, off);
  if (j == 0) csqh[k] = -0.5f * s;
}

// K2: LDS-resident codebook halves (hi+lo = 128KB/half, XOR-swizzled), 2 passes,
// 4 barriers total. 1024 threads = 16 waves; each wave owns 32 rows.
// acc = zhi*chi + zlo*chi + zhi*clo - 0.5*|c|^2 (err ~ zlo*clo ~ 6e-7 std).
// Fused: loss partial (||z-e||^2 = ||z||^2 - 2*m1), z_q gather/write, per-row flag byte.
__launch_bounds__(1024, 4)
__global__ void k2_argmin(const float* __restrict__ z,
                          const unsigned short* __restrict__ cb_hi,
                          const unsigned short* __restrict__ cb_lo,
                          const float* __restrict__ csqh,
                          const float* __restrict__ cb,
                          float* __restrict__ out_idx,
                          float* __restrict__ zq,
                          unsigned char* __restrict__ fl,
                          float* __restrict__ partials) {
  __shared__ unsigned short lds_cb[2 * HALF * DIM];  // 128 KB: [split][code][chunk] swizzled
  __shared__ float lds_csq[KC];                      // 4 KB; reused as idxL after compute
  __shared__ float wpart[16];

  const int tid  = threadIdx.x;
  const int lane = tid & 63;
  const int wv   = tid >> 6;    // 0..15
  const int lg   = lane >> 4;   // k-chunk group
  const int lr   = lane & 15;
  const int row0 = blockIdx.x * ROWS_PER_BLOCK;

  // Stage one codebook half: 8192 slots x 16B. slot = split*4096 + cl*8 + ch holds
  // global chunk ch^(cl&7) (XOR involution; pre-swizzled source, linear LDS dest).
#define STAGE(h)                                                              \
  {                                                                           \
    _Pragma("unroll")                                                         \
    for (int p = 0; p < 8; ++p) {                                             \
      const int linear = p * 1024 + tid;                                      \
      const int ch = linear & 7;                                              \
      const int cl = (linear >> 3) & (HALF - 1);                              \
      const int split = linear >> 12;                                         \
      const unsigned short* src =                                             \
          (split ? cb_lo : cb_hi) + ((h) * HALF + cl) * DIM + ((ch ^ (cl & 7)) * 8); \
      gll16(src, (char*)lds_cb + linear * 16);                                \
    }                                                                         \
  }

  STAGE(0);
  if (tid < KC / 4) ((f32x4*)lds_csq)[tid] = ((const f32x4*)csqh)[tid];

  // Z fragments: hi = trunc, lo = RN(resid) via v_cvt_pk_bf16_f32; also ||z||^2.
  short8 zhi[2][2], zlo[2][2];
  float zsq[2];
  #pragma unroll
  for (int rt = 0; rt < 2; ++rt) {
    const int row = row0 + wv * 32 + rt * 16 + lr;
    float sq = 0.0f;
    #pragma unroll
    for (int ks = 0; ks < 2; ++ks) {
      const float* p = z + (size_t)row * DIM + ks * 32 + lg * 8;
      const f32x4 va = *(const f32x4*)p;
      const f32x4 vb = *(const f32x4*)(p + 4);
      sq = fmaf(va[0], va[0], sq); sq = fmaf(va[1], va[1], sq);
      sq = fmaf(va[2], va[2], sq); sq = fmaf(va[3], va[3], sq);
      sq = fmaf(vb[0], vb[0], sq); sq = fmaf(vb[1], vb[1], sq);
      sq = fmaf(vb[2], vb[2], sq); sq = fmaf(vb[3], vb[3], sq);
      union { uint32_t w[4]; short8 s8; } H, L;
      #pragma unroll
      for (int pr = 0; pr < 4; ++pr) {
        const float f0 = (pr < 2) ? va[2 * pr]     : vb[2 * pr - 4];
        const float f1 = (pr < 2) ? va[2 * pr + 1] : vb[2 * pr - 3];
        const uint32_t u0 = __float_as_uint(f0);
        const uint32_t u1 = __float_as_uint(f1);
        H.w[pr] = __builtin_amdgcn_perm(u1, u0, 0x07060302u);  // {u1.hi16, u0.hi16}
        const float l0 = f0 - __uint_as_float(u0 & 0xffff0000u);
        const float l1 = f1 - __uint_as_float(u1 & 0xffff0000u);
        uint32_t lw;
        asm("v_cvt_pk_bf16_f32 %0, %1, %2" : "=v"(lw) : "v"(l0), "v"(l1));
        L.w[pr] = lw;
      }
      zhi[rt][ks] = H.s8;
      zlo[rt][ks] = L.s8;
    }
    zsq[rt] = sq;
  }

  float M1[2] = {-3.0e38f, -3.0e38f}, M2[2] = {-3.0e38f, -3.0e38f};
  int I1[2] = {0, 0};

  // swizzle XOR loop-invariant: (ct*16+lr)&7 == lr&7
  const int offh0 = lr * 128 + ((lg)     ^ (lr & 7)) * 16;
  const int offh1 = lr * 128 + ((4 + lg) ^ (lr & 7)) * 16;
  const int offl0 = offh0 + HALF * 128;   // +64KB: lo split
  const int offl1 = offh1 + HALF * 128;

  #pragma unroll
  for (int h = 0; h < 2; ++h) {
    __syncthreads();                       // staged half landed (vmcnt drained by barrier)
    #pragma unroll 2
    for (int ct = 0; ct < HALF / 16; ++ct) {
      const int cbase = h * HALF + ct * 16 + lg * 4;
      const f32x4 init = *(const f32x4*)&lds_csq[cbase];   // -0.5*c^2 per acc reg
      const char* base = (const char*)lds_cb + ct * 2048;
      const short8 ch0 = *(const short8*)(base + offh0);
      const short8 ch1 = *(const short8*)(base + offh1);
      const short8 cl0 = *(const short8*)(base + offl0);
      const short8 cl1 = *(const short8*)(base + offl1);
      #pragma unroll
      for (int rt = 0; rt < 2; ++rt) {
        f32x4 acc = init;
        acc = __builtin_amdgcn_mfma_f32_16x16x32_bf16(ch0, zhi[rt][0], acc, 0, 0, 0);
        acc = __builtin_amdgcn_mfma_f32_16x16x32_bf16(ch1, zhi[rt][1], acc, 0, 0, 0);
        acc = __builtin_amdgcn_mfma_f32_16x16x32_bf16(ch0, zlo[rt][0], acc, 0, 0, 0);
        acc = __builtin_amdgcn_mfma_f32_16x16x32_bf16(ch1, zlo[rt][1], acc, 0, 0, 0);
        acc = __builtin_amdgcn_mfma_f32_16x16x32_bf16(cl0, zhi[rt][0], acc, 0, 0, 0);
        acc = __builtin_amdgcn_mfma_f32_16x16x32_bf16(cl1, zhi[rt][1], acc, 0, 0, 0);
        #pragma unroll
        for (int j = 0; j < 4; ++j) {
          const float s = acc[j];
          M2[rt] = __builtin_amdgcn_fmed3f(s, M1[rt], M2[rt]);  // invariant M1>=M2
          const bool take = s > M1[rt];
          M1[rt] = fmaxf(s, M1[rt]);
          I1[rt] = take ? (cbase + j) : I1[rt];
        }
      }
    }
    __syncthreads();                       // all reads of this half done
    if (h == 0) STAGE(1);                  // overwrite with second half
  }
#undef STAGE

  // Cross-lane combine over lg groups (^16, ^32); butterfly => all lanes hold result.
  float M1b[2], M2b[2], loss01 = 0.0f;
  int idxr[2];
  #pragma unroll
  for (int rt = 0; rt < 2; ++rt) {
    float m1 = M1[rt], m2 = M2[rt];
    int i1 = I1[rt];
    #pragma unroll
    for (int off = 16; off <= 32; off <<= 1) {
      const float o1 = __shfl_xor(m1, off);
      const float o2 = __shfl_xor(m2, off);
      const int   oi = __shfl_xor(i1, off);
      m2 = fmaxf(fmaxf(m2, o2), fminf(m1, o1));
      const bool take = (o1 > m1) || (o1 == m1 && oi < i1);
      if (take) { m1 = o1; i1 = oi; }
    }
    float zs = zsq[rt];
    zs += __shfl_xor(zs, 16);
    zs += __shfl_xor(zs, 32);
    M1b[rt] = m1; M2b[rt] = m2; idxr[rt] = i1;
    loss01 += zs - 2.0f * m1;           // ||z-e||^2 (x4 duplicated across lg groups)
  }

  int* idxL = (int*)lds_csq;            // safe: last csq read was before the post-compute barrier
  if (lane < 16) {
    #pragma unroll
    for (int rt = 0; rt < 2; ++rt) {
      const int r = wv * 32 + rt * 16 + lr;
      out_idx[row0 + r] = (float)idxr[rt];
      idxL[r] = idxr[rt];
      fl[row0 + r] = (M1b[rt] - M2b[rt] < TAU) ? 1 : 0;   // no atomics
    }
  }
  float lsum = loss01;
  #pragma unroll
  for (int off = 1; off <= 32; off <<= 1) lsum += __shfl_xor(lsum, off);
  if (lane == 0) wpart[wv] = lsum * 0.25f;   // /4: lg-group duplication
  __syncthreads();
  if (tid == 0) {
    float s = 0.0f;
    #pragma unroll
    for (int i = 0; i < 16; ++i) s += wpart[i];
    partials[blockIdx.x] = s;
  }
  // z_q gather + write: 2 threads per row x 8 f32x4 = full 64 floats (R7 bug fixed)
  {
    const int r2 = tid >> 1, halfq = tid & 1;
    const int idx = idxL[r2];
    const f32x4* src = (const f32x4*)(cb + (size_t)idx * DIM + halfq * 32);
    f32x4* dst = (f32x4*)(zq + (size_t)(row0 + r2) * DIM + halfq * 32);
    #pragma unroll
    for (int j = 0; j < 8; ++j) dst[j] = src[j];
  }
}

// K3: ballot-scan flag bytes in 64-row stripes; exact f32 re-argmin per set bit.
// Fixes out_idx AND z_q. No atomics anywhere.
__global__ void k3_rescue(const float* __restrict__ z,
                          const float* __restrict__ cb,
                          const float* __restrict__ csqh,
                          const unsigned char* __restrict__ fl,
                          float* __restrict__ out_idx,
                          float* __restrict__ zq,
                          int nstripes) {
  const int lane = threadIdx.x & 63;
  const int w = blockIdx.x * 4 + (threadIdx.x >> 6);
  const int nw = gridDim.x * 4;
  for (int s = w; s < nstripes; s += nw) {
    const int base = s * 64;
    unsigned long long mask = __ballot(fl[base + lane] != 0);
    while (mask) {
      const int bit = __ffsll(mask) - 1;
      mask &= mask - 1;
      const int row = base + bit;
      const f32x4* zr4 = (const f32x4*)(z + (size_t)row * DIM);
      float m1 = -3.0e38f;
      int i1 = 0;
      for (int kk = 0; kk < 16; ++kk) {
        const int k = lane * 16 + kk;
        const f32x4* cp = (const f32x4*)(cb + (size_t)k * DIM);
        float acc = csqh[k];
        #pragma unroll
        for (int j4 = 0; j4 < DIM / 4; ++j4) {
          const f32x4 c4 = cp[j4];
          const f32x4 z4 = zr4[j4];
          acc = fmaf(z4[0], c4[0], acc);
          acc = fmaf(z4[1], c4[1], acc);
          acc = fmaf(z4[2], c4[2], acc);
          acc = fmaf(z4[3], c4[3], acc);
        }
        if (acc > m1) { m1 = acc; i1 = k; }
      }
      #pragma unroll
      for (int off = 32; off >= 1; off >>= 1) {    // butterfly: all lanes get winner
        const float o1 = __shfl_xor(m1, off);
        const int   oi = __shfl_xor(i1, off);
        if (o1 > m1 || (o1 == m1 && oi < i1)) { m1 = o1; i1 = oi; }
      }
      if (lane == 0) out_idx[row] = (float)i1;
      if (lane < 16)
        ((f32x4*)(zq + (size_t)row * DIM))[lane] =
            ((const f32x4*)(cb + (size_t)i1 * DIM))[lane];
    }
  }
}

// K5: reduce 256 block partials -> loss (single block, deterministic tree)
__global__ void k5_reduce(const float* __restrict__ partials,
                          float* __restrict__ loss_slot,
                          float scale, int nb) {
  __shared__ float wsum[4];
  const int tid = threadIdx.x;
  float s = 0.0f;
  for (int i = tid; i < nb / 4; i += 256) {
    const f32x4 v = ((const f32x4*)partials)[i];
    s += (v[0] + v[1]) + (v[2] + v[3]);
  }
  #pragma unroll
  for (int off = 32; off >= 1; off >>= 1) s += __shfl_xor(s, off);
  if ((tid & 63) == 0) wsum[tid >> 6] = s;
  __syncthreads();
  if (tid == 0) *loss_slot = (wsum[0] + wsum[1] + wsum[2] + wsum[3]) * scale;
}

extern "C" void kernel_launch(void* const* d_in, const int* in_sizes, int n_in,
                              void* d_out, int out_size, void* d_ws, size_t ws_size,
                              hipStream_t stream) {
  const float* z  = (const float*)d_in[0];
  const float* cb = (const float*)d_in[1];
  const int N = in_sizes[0] / DIM;  // 131072

  float* out       = (float*)d_out;
  float* out_idx   = out;                          // [0, N): indices as float
  float* zq        = out + N;                      // [N, N + N*64): z_q
  float* loss_slot = out + N + (size_t)N * DIM;    // last element: vq_loss

  unsigned short* cb_hi = (unsigned short*)d_ws;   // 128 KB
  unsigned short* cb_lo = cb_hi + KC * DIM;        // 128 KB
  float* csqh = (float*)(cb_lo + KC * DIM);        // 4 KB
  float* partials = csqh + KC;                     // 1 KB (256 blocks)
  unsigned char* fl = (unsigned char*)(partials + 256);  // N bytes = 128 KB

  const int nb2 = N / ROWS_PER_BLOCK;              // 256 blocks
  const float scale = 1.25f / ((float)N * (float)DIM);  // (1+BETA)/(N*d)

  k1_prep<<<KC, DIM, 0, stream>>>(cb, cb_hi, cb_lo, csqh);
  k2_argmin<<<nb2, 1024, 0, stream>>>(z, cb_hi, cb_lo, csqh, cb, out_idx, zq, fl, partials);
  k3_rescue<<<256, 256, 0, stream>>>(z, cb, csqh, fl, out_idx, zq, N / 64);
  k5_reduce<<<1, 256, 0, stream>>>(partials, loss_slot, scale, nb2);
}

// Round 11
// 185.742 us; speedup vs baseline: 2.0818x; 1.0868x over previous
//
#include <hip/hip_runtime.h>
#include <stdint.h>

#define DIM 64
#define KC 1024
#define QTR 256                 // codes resident per pass
#define NPASS (KC / QTR)        // 4
#define RPB 256                 // rows per block
#define TAU 5.0e-5f             // margin flag (acc = dist/2 scale); 3-split err std ~6e-7

typedef float f32x4 __attribute__((ext_vector_type(4)));
typedef short short8 __attribute__((ext_vector_type(8)));

__device__ __forceinline__ unsigned short bf16_rn(float f) {
  union { float f; uint32_t u; } v; v.f = f;
  uint32_t u = v.u;
  uint32_t r = u + 0x7fffu + ((u >> 16) & 1u);
  return (unsigned short)(r >> 16);
}
__device__ __forceinline__ float bf16_f32(unsigned short h) {
  union { uint32_t u; float f; } v; v.u = ((uint32_t)h) << 16;
  return v.f;
}
__device__ __forceinline__ void gll16(const void* g, void* l) {
  __builtin_amdgcn_global_load_lds(
      (const __attribute__((address_space(1))) void*)g,
      (__attribute__((address_space(3))) void*)l, 16, 0, 0);
}

// K1: codebook -> bf16 hi/lo split, csqh = -0.5*sum(c^2) exact f32.
__global__ void k1_prep(const float* __restrict__ cb,
                        unsigned short* __restrict__ cb_hi,
                        unsigned short* __restrict__ cb_lo,
                        float* __restrict__ csqh) {
  const int k = blockIdx.x, j = threadIdx.x;
  const float c = cb[k * DIM + j];
  const unsigned short hi = bf16_rn(c);
  cb_hi[k * DIM + j] = hi;
  cb_lo[k * DIM + j] = bf16_rn(c - bf16_f32(hi));
  float s = c * c;
  #pragma unroll
  for (int off = 32; off >= 1; off >>= 1) s += __shfl_xor(s, off);
  if (j == 0) csqh[k] = -0.5f * s;
}

// K2: 3-split bf16 MFMA argmin, quad-level tracking + exact f32 re-rank of the
// winning 4-code group. 512 blocks x 512 threads (8 waves, 2 blocks/CU).
// Codebook staged in 4 quarter passes (64KB LDS, XOR-swizzled, gll16 direct).
__launch_bounds__(512, 4)
__global__ void k2_argmin(const float* __restrict__ z,
                          const unsigned short* __restrict__ cb_hi,
                          const unsigned short* __restrict__ cb_lo,
                          const float* __restrict__ csqh,
                          const float* __restrict__ cb,
                          float* __restrict__ out_idx,
                          float* __restrict__ zq,
                          unsigned char* __restrict__ fl,
                          float* __restrict__ partials) {
  __shared__ unsigned short lds_cb[2 * QTR * DIM];  // 64 KB: [split][code][chunk] swizzled
  __shared__ float lds_csq[KC];                     // 4 KB (intact through epilogue)

  const int tid  = threadIdx.x;
  const int lane = tid & 63;
  const int wv   = tid >> 6;    // 0..7
  const int lg   = lane >> 4;   // k-chunk group
  const int lr   = lane & 15;
  const int row0 = blockIdx.x * RPB;

  // Stage quarter pp: 4096 slots x 16B; slot (split, cl, ch) holds global chunk
  // ch^(cl&7) of code pp*256+cl (involution; per-lane source, lane-linear dest).
#define STAGE(pp)                                                             \
  {                                                                           \
    _Pragma("unroll")                                                         \
    for (int p2 = 0; p2 < 8; ++p2) {                                          \
      const int linear = p2 * 512 + tid;                                      \
      const int ch = linear & 7;                                              \
      const int cl = (linear >> 3) & (QTR - 1);                               \
      const int split = linear >> 11;                                         \
      const unsigned short* src =                                             \
          (split ? cb_lo : cb_hi) + ((pp) * QTR + cl) * DIM + ((ch ^ (cl & 7)) * 8); \
      gll16(src, (char*)lds_cb + linear * 16);                                \
    }                                                                         \
  }

  STAGE(0);
  if (tid < KC / 4) ((f32x4*)lds_csq)[tid] = ((const f32x4*)csqh)[tid];

  // Z fragments: hi = trunc, lo = RN(resid); also exact ||z||^2 partials.
  short8 zhi[2][2], zlo[2][2];
  float zsq[2];
  #pragma unroll
  for (int rt = 0; rt < 2; ++rt) {
    const int row = row0 + wv * 32 + rt * 16 + lr;
    float sq = 0.0f;
    #pragma unroll
    for (int ks = 0; ks < 2; ++ks) {
      const float* p = z + (size_t)row * DIM + ks * 32 + lg * 8;
      const f32x4 va = *(const f32x4*)p;
      const f32x4 vb = *(const f32x4*)(p + 4);
      sq = fmaf(va[0], va[0], sq); sq = fmaf(va[1], va[1], sq);
      sq = fmaf(va[2], va[2], sq); sq = fmaf(va[3], va[3], sq);
      sq = fmaf(vb[0], vb[0], sq); sq = fmaf(vb[1], vb[1], sq);
      sq = fmaf(vb[2], vb[2], sq); sq = fmaf(vb[3], vb[3], sq);
      union { uint32_t w[4]; short8 s8; } H, L;
      #pragma unroll
      for (int pr = 0; pr < 4; ++pr) {
        const float f0 = (pr < 2) ? va[2 * pr]     : vb[2 * pr - 4];
        const float f1 = (pr < 2) ? va[2 * pr + 1] : vb[2 * pr - 3];
        const uint32_t u0 = __float_as_uint(f0);
        const uint32_t u1 = __float_as_uint(f1);
        H.w[pr] = __builtin_amdgcn_perm(u1, u0, 0x07060302u);
        const float l0 = f0 - __uint_as_float(u0 & 0xffff0000u);
        const float l1 = f1 - __uint_as_float(u1 & 0xffff0000u);
        uint32_t lw;
        asm("v_cvt_pk_bf16_f32 %0, %1, %2" : "=v"(lw) : "v"(l0), "v"(l1));
        L.w[pr] = lw;
      }
      zhi[rt][ks] = H.s8;
      zlo[rt][ks] = L.s8;
    }
    zsq[rt] = sq;
  }

  float M1[2] = {-3.0e38f, -3.0e38f}, M2[2] = {-3.0e38f, -3.0e38f};
  int C1[2] = {0, 0};

  // swizzle XOR loop-invariant: (ct*16+lr)&7 == lr&7
  const int offh0 = lr * 128 + ((lg)     ^ (lr & 7)) * 16;
  const int offh1 = lr * 128 + ((4 + lg) ^ (lr & 7)) * 16;
  const int offl0 = offh0 + QTR * 128;   // +32KB: lo split
  const int offl1 = offh1 + QTR * 128;

  for (int p = 0; p < NPASS; ++p) {
    __syncthreads();                       // staged quarter landed
    #pragma unroll 4
    for (int ct = 0; ct < QTR / 16; ++ct) {
      const int cbase = p * QTR + ct * 16 + lg * 4;   // quad id (4 codes)
      const f32x4 init = *(const f32x4*)&lds_csq[cbase];
      const char* base = (const char*)lds_cb + ct * 2048;
      const short8 ch0 = *(const short8*)(base + offh0);
      const short8 ch1 = *(const short8*)(base + offh1);
      const short8 cl0 = *(const short8*)(base + offl0);
      const short8 cl1 = *(const short8*)(base + offl1);
      #pragma unroll
      for (int rt = 0; rt < 2; ++rt) {
        f32x4 acc = init;
        acc = __builtin_amdgcn_mfma_f32_16x16x32_bf16(ch0, zhi[rt][0], acc, 0, 0, 0);
        acc = __builtin_amdgcn_mfma_f32_16x16x32_bf16(ch1, zhi[rt][1], acc, 0, 0, 0);
        acc = __builtin_amdgcn_mfma_f32_16x16x32_bf16(ch0, zlo[rt][0], acc, 0, 0, 0);
        acc = __builtin_amdgcn_mfma_f32_16x16x32_bf16(ch1, zlo[rt][1], acc, 0, 0, 0);
        acc = __builtin_amdgcn_mfma_f32_16x16x32_bf16(cl0, zhi[rt][0], acc, 0, 0, 0);
        acc = __builtin_amdgcn_mfma_f32_16x16x32_bf16(cl1, zhi[rt][1], acc, 0, 0, 0);
        const float qm = fmaxf(fmaxf(acc[0], acc[1]), fmaxf(acc[2], acc[3]));
        M2[rt] = __builtin_amdgcn_fmed3f(qm, M1[rt], M2[rt]);  // 2nd-best quadmax
        const bool take = qm > M1[rt];
        M1[rt] = fmaxf(qm, M1[rt]);
        C1[rt] = take ? cbase : C1[rt];
      }
    }
    __syncthreads();                       // all reads of this quarter done
    if (p < NPASS - 1) STAGE(p + 1);
  }
#undef STAGE

  // Butterfly over lg groups (^16, ^32): winner quad, runner-up quadmax, zsq.
  float m1f[2], m2f[2], zsf[2];
  int cwf[2];
  #pragma unroll
  for (int rt = 0; rt < 2; ++rt) {
    float m1 = M1[rt], m2 = M2[rt];
    int c1 = C1[rt];
    #pragma unroll
    for (int off = 16; off <= 32; off <<= 1) {
      const float o1 = __shfl_xor(m1, off);
      const float o2 = __shfl_xor(m2, off);
      const int   oc = __shfl_xor(c1, off);
      m2 = fmaxf(fmaxf(m2, o2), fminf(m1, o1));
      const bool take = (o1 > m1) || (o1 == m1 && oc < c1);
      if (take) { m1 = o1; c1 = oc; }
    }
    float zs = zsq[rt];
    zs += __shfl_xor(zs, 16);
    zs += __shfl_xor(zs, 32);
    m1f[rt] = m1; m2f[rt] = m2; cwf[rt] = c1; zsf[rt] = zs;
  }

  // Scratch overlays lds_cb (all LDS reads of it are behind the last barrier).
  float* m2S   = (float*)lds_cb;        // [256]
  int*   cwS   = (int*)(m2S + 256);     // [256]
  float* zsS   = (float*)(cwS + 256);   // [256]
  float* lossS = zsS + 256;             // [256]
  int*   jS    = (int*)(lossS + 256);   // [256]

  if (lg == 0) {
    #pragma unroll
    for (int rt = 0; rt < 2; ++rt) {
      const int r = wv * 32 + rt * 16 + lr;
      m2S[r] = m2f[rt];
      cwS[r] = cwf[rt];
      zsS[r] = zsf[rt];
    }
  }
  __syncthreads();

  // Exact f32 re-rank of the winning quad: 2 threads/row, 2 codes each.
  {
    const int row = tid >> 1, pr = tid & 1;
    const int cw = cwS[row];
    const int c0 = cw + pr * 2, c1i = c0 + 1;
    const f32x4* zr4 = (const f32x4*)(z + (size_t)(row0 + row) * DIM);
    const f32x4* cb0 = (const f32x4*)(cb + (size_t)c0 * DIM);
    const f32x4* cb1 = (const f32x4*)(cb + (size_t)c1i * DIM);
    float s0 = lds_csq[c0], s1 = lds_csq[c1i];
    #pragma unroll
    for (int j4 = 0; j4 < 16; ++j4) {
      const f32x4 zv = zr4[j4], a = cb0[j4], b = cb1[j4];
      s0 = fmaf(zv[0], a[0], s0); s0 = fmaf(zv[1], a[1], s0);
      s0 = fmaf(zv[2], a[2], s0); s0 = fmaf(zv[3], a[3], s0);
      s1 = fmaf(zv[0], b[0], s1); s1 = fmaf(zv[1], b[1], s1);
      s1 = fmaf(zv[2], b[2], s1); s1 = fmaf(zv[3], b[3], s1);
    }
    float h, l; int jh;
    if (s0 >= s1) { h = s0; l = s1; jh = c0; } else { h = s1; l = s0; jh = c1i; }
    const float oh = __shfl_xor(h, 1);
    const float ol = __shfl_xor(l, 1);
    const int   oj = __shfl_xor(jh, 1);
    const bool takeo = (oh > h) || (oh == h && oj < jh);
    const float sbest = takeo ? oh : h;
    const int   jbest = takeo ? oj : jh;
    const float second = fmaxf(fmaxf(fminf(h, oh), fmaxf(l, ol)), m2S[row]);
    if (pr == 0) {
      out_idx[row0 + row] = (float)jbest;
      jS[row] = jbest;
      fl[row0 + row] = (sbest - second < TAU) ? 1 : 0;
      lossS[row] = zsS[row] - 2.0f * sbest;    // exact ||z-e||^2
    }
  }
  __syncthreads();

  // Deterministic block loss reduce (wave 0).
  if (tid < 64) {
    float s = (lossS[tid] + lossS[tid + 64]) + (lossS[tid + 128] + lossS[tid + 192]);
    #pragma unroll
    for (int off = 32; off >= 1; off >>= 1) s += __shfl_xor(s, off);
    if (tid == 0) partials[blockIdx.x] = s;
  }
  // z_q write: 2 threads/row x 32 floats from the exact winner.
  {
    const int row = tid >> 1, pr = tid & 1;
    const int jb = jS[row];
    const f32x4* src = (const f32x4*)(cb + (size_t)jb * DIM + pr * 32);
    f32x4* dst = (f32x4*)(zq + (size_t)(row0 + row) * DIM + pr * 32);
    #pragma unroll
    for (int j = 0; j < 8; ++j) dst[j] = src[j];
  }
}

// K3: block 0 reduces loss partials; all blocks ballot-scan flag bytes and do
// exact f32 re-argmin per flagged row (fixes out_idx AND z_q). No atomics.
__global__ void k3_rescue(const float* __restrict__ z,
                          const float* __restrict__ cb,
                          const float* __restrict__ csqh,
                          const unsigned char* __restrict__ fl,
                          float* __restrict__ out_idx,
                          float* __restrict__ zq,
                          const float* __restrict__ partials,
                          float* __restrict__ loss_slot,
                          float scale, int nblocks, int nstripes) {
  if (blockIdx.x == 0 && threadIdx.x < 64) {
    const int lane = threadIdx.x;
    float s = 0.0f;
    for (int i = lane; i < nblocks; i += 64) s += partials[i];
    #pragma unroll
    for (int off = 32; off >= 1; off >>= 1) s += __shfl_xor(s, off);
    if (lane == 0) *loss_slot = s * scale;
  }
  const int lane = threadIdx.x & 63;
  const int w = blockIdx.x * 4 + (threadIdx.x >> 6);
  const int nw = gridDim.x * 4;
  for (int st = w; st < nstripes; st += nw) {
    const int base = st * 64;
    unsigned long long mask = __ballot(fl[base + lane] != 0);
    while (mask) {
      const int bit = __ffsll(mask) - 1;
      mask &= mask - 1;
      const int row = base + bit;
      const f32x4* zr4 = (const f32x4*)(z + (size_t)row * DIM);
      float m1 = -3.0e38f;
      int i1 = 0;
      for (int kk = 0; kk < 16; ++kk) {
        const int k = lane * 16 + kk;
        const f32x4* cp = (const f32x4*)(cb + (size_t)k * DIM);
        float acc = csqh[k];
        #pragma unroll
        for (int j4 = 0; j4 < DIM / 4; ++j4) {
          const f32x4 c4 = cp[j4];
          const f32x4 z4 = zr4[j4];
          acc = fmaf(z4[0], c4[0], acc);
          acc = fmaf(z4[1], c4[1], acc);
          acc = fmaf(z4[2], c4[2], acc);
          acc = fmaf(z4[3], c4[3], acc);
        }
        if (acc > m1) { m1 = acc; i1 = k; }
      }
      #pragma unroll
      for (int off = 32; off >= 1; off >>= 1) {
        const float o1 = __shfl_xor(m1, off);
        const int   oi = __shfl_xor(i1, off);
        if (o1 > m1 || (o1 == m1 && oi < i1)) { m1 = o1; i1 = oi; }
      }
      if (lane == 0) out_idx[row] = (float)i1;
      if (lane < 16)
        ((f32x4*)(zq + (size_t)row * DIM))[lane] =
            ((const f32x4*)(cb + (size_t)i1 * DIM))[lane];
    }
  }
}

extern "C" void kernel_launch(void* const* d_in, const int* in_sizes, int n_in,
                              void* d_out, int out_size, void* d_ws, size_t ws_size,
                              hipStream_t stream) {
  const float* z  = (const float*)d_in[0];
  const float* cb = (const float*)d_in[1];
  const int N = in_sizes[0] / DIM;  // 131072

  float* out       = (float*)d_out;
  float* out_idx   = out;                          // [0, N): indices as float
  float* zq        = out + N;                      // [N, N + N*64): z_q
  float* loss_slot = out + N + (size_t)N * DIM;    // last element: vq_loss

  unsigned short* cb_hi = (unsigned short*)d_ws;   // 128 KB
  unsigned short* cb_lo = cb_hi + KC * DIM;        // 128 KB
  float* csqh = (float*)(cb_lo + KC * DIM);        // 4 KB
  float* partials = csqh + KC;                     // 2 KB (512 blocks)
  unsigned char* fl = (unsigned char*)(partials + 512);  // 128 KB

  const int nb2 = N / RPB;                         // 512 blocks
  const float scale = 1.25f / ((float)N * (float)DIM);  // (1+BETA)/(N*d)

  k1_prep<<<KC, DIM, 0, stream>>>(cb, cb_hi, cb_lo, csqh);
  k2_argmin<<<nb2, 512, 0, stream>>>(z, cb_hi, cb_lo, csqh, cb, out_idx, zq, fl, partials);
  k3_rescue<<<256, 256, 0, stream>>>(z, cb, csqh, fl, out_idx, zq, partials, loss_slot,
                                     scale, nb2, N / 64);
}